// Round 1
// baseline (143.925 us; speedup 1.0000x reference)
//
#include <hip/hip_runtime.h>
#include <cstdint>

typedef unsigned short u16;
typedef unsigned int   u32;
typedef __bf16 bf16x8 __attribute__((ext_vector_type(8)));
typedef float  f32x16 __attribute__((ext_vector_type(16)));

#define OUT1 984064   // 16*248*248
#define OUT2 350464   // 16*16*37*37

// workspace layout (bytes)
#define XIMG_ELEMS (8*16*248*264)              // 8 shifted bf16 copies of x1
#define TMPL_OFFB  (XIMG_ELEMS*2)              // 16760832
#define TMPL_ELEMS (16*216*224)                // zero-padded templates
#define PART_OFFB  (TMPL_OFFB + TMPL_ELEMS*2)  // 18309120
#define PART_ELEMS (6*OUT2)                    // [3 uq][2 gp] partial slabs
#define EFF_OFFB   (PART_OFFB + PART_ELEMS*4)  // 26720256 ; +5184 B eff filters

// ---------------- k0: zero partial slabs + build effective 16x9x9 filters ----
__global__ void k0_init(const float* __restrict__ ft, const float* __restrict__ fnt,
                        float* __restrict__ partial, float* __restrict__ effw) {
  int t = blockIdx.x * 256 + threadIdx.x;
  for (int z = t; z < PART_ELEMS; z += gridDim.x * 256) partial[z] = 0.f;
  if (blockIdx.x == 0) {
    for (int idx = threadIdx.x; idx < 1296; idx += 256) {
      int c = idx / 81, s = idx - (idx / 81) * 81;
      // temp channels: depth-2 kernel on duplicated x == (f0+f1), then /2 folded in
      effw[idx] = (c < 8) ? 0.5f * (ft[c*162 + s] + ft[c*162 + 81 + s])
                          : fnt[(c-8)*81 + s];
    }
  }
}

// ---------------- k1: f32 conv + relu + channel-normalize + bf16 packing -----
__global__ __launch_bounds__(256) void k1_conv(
    const float* __restrict__ x, const float* __restrict__ effw,
    float* __restrict__ out1, u16* __restrict__ Ximg, u16* __restrict__ TmplP) {
  __shared__ float xt[24][25];
  const int tid = threadIdx.x;
  const int lx = tid & 15, ly = tid >> 4;
  const int bx = blockIdx.x, by = blockIdx.y;
  for (int idx = tid; idx < 576; idx += 256) {
    int ry = idx / 24, rx = idx - ry * 24;
    int gy = by*16 + ry; gy = gy > 255 ? 255 : gy;
    int gx = bx*16 + rx; gx = gx > 255 ? 255 : gx;
    xt[ry][rx] = x[gy*256 + gx];
  }
  __syncthreads();
  const int xg = bx*16 + lx, yg = by*16 + ly;
  if (yg >= 248) return;
  float s[16];
#pragma unroll
  for (int c = 0; c < 16; ++c) s[c] = 0.f;
  const bool valid = (xg < 248);
  if (valid) {
#pragma unroll
    for (int u = 0; u < 9; ++u)
#pragma unroll
      for (int v = 0; v < 9; ++v) {
        float xv = xt[ly + u][lx + v];
#pragma unroll
        for (int c = 0; c < 16; ++c)   // effw[...] is wave-uniform -> s_load path
          s[c] = __builtin_fmaf(xv, effw[c*81 + u*9 + v], s[c]);
      }
    float sum = 2.2204460492503131e-16f;  // EPS, matches reference
#pragma unroll
    for (int c = 0; c < 16; ++c) { s[c] = s[c] > 0.f ? s[c] : 0.f; sum += s[c]; }
    float inv = 1.f / sum;
#pragma unroll
    for (int c = 0; c < 16; ++c) s[c] *= inv;
  }
#pragma unroll
  for (int c = 0; c < 16; ++c) {
    u16 hb = 0;
    if (valid) {
      out1[c*61504 + yg*248 + xg] = s[c];
      u32 ub = __builtin_bit_cast(u32, s[c]);
      hb = (u16)((ub + 0x7fffu + ((ub >> 16) & 1u)) >> 16);  // bf16 RNE
    }
    // 8 column-shifted bf16 copies (keeps global_load_lds sources 16B-aligned)
#pragma unroll
    for (int d = 0; d < 8; ++d) {
      int wp = xg - d;
      if (wp >= 0 && wp < 264)
        Ximg[((d*16 + c)*248 + yg)*264 + wp] = hb;   // hb==0 writes the pads
    }
    // templates = center crop [18:230), u padded to 216 rows, v to 224 (zeros)
    if (xg >= 18 && xg < 242 && yg >= 18 && yg < 234) {
      u16 tv = (xg < 230 && yg < 230) ? hb : (u16)0;
      TmplP[(c*216 + (yg - 18))*224 + (xg - 18)] = tv;
    }
  }
}

// ---------------- k2: MFMA correlation ---------------------------------------
// WG = (j, chain-group g of 5 even i0's, u-quarter uq). 4 waves split the
// 36-step u0 range (9 steps each, padded past 106 with zero templates).
// MFMA 32x32x16: A rows=(uu,n) two consecutive image rows x 16 maps,
// B cols=(p,o) two consecutive template rows x 16 templates; slot (uu,p)
// contributes to output row i0+uu-p with complementary u-parity.
#define F_LD(k,m,c) fl[(k)*1024 + (((m)&3) + 4*((m)>>3))*64 + ((c) + 32*(((m)>>2)&1))]

__global__ __launch_bounds__(256, 2) void k2_corr(
    const u16* __restrict__ Ximg, const u16* __restrict__ TmplP,
    float* __restrict__ partial) {
  extern __shared__ u16 lds[];   // [16][80*16+8] img  +  [16][72*16+8] tmpl
  const int wg   = blockIdx.x;
  const int j    = wg % 37;
  const int rest = wg / 37;          // 0..11
  const int g    = rest & 3;
  const int uq   = rest >> 2;        // 0..2
  const int T0   = 36 * uq;
  const int R0   = 10*g + 2*T0;
  const int U0   = 2*T0;
  const int tid  = threadIdx.x;
  const int lane = tid & 63;
  const int w    = tid >> 6;
  const int dlt  = j & 7;
  const int jb   = j - dlt;          // multiple of 8 -> 16B-aligned sources

  const int fn16 = lane & 15;
  const int fuu  = (lane >> 4) & 1;
  const int fg   = lane >> 5;
  const int aBase = fn16*1288 + fuu*16 + fg*8 + 288*w;           // elems
  const int bBase = 20608 + fn16*1160 + fuu*16 + fg*8 + 288*w;   // elems

  // sv-invariant per-lane staging source offsets
  int ioff[12], toff[12];
#pragma unroll
  for (int q = 0; q < 4; ++q) {
    const int n = w*4 + q;
#pragma unroll
    for (int inst = 0; inst < 3; ++inst) {
      int chunk = inst*64 + lane;
      int rr = chunk >> 1, gg = chunk & 1;
      int row = R0 + rr; row = row > 247 ? 247 : row;   // clamped rows never read
      ioff[q*3 + inst] = ((dlt*16 + n)*248 + row)*264 + jb + gg*8;
      toff[q*3 + inst] = (n*216 + U0 + rr)*224 + gg*8;  // OOB lanes are exec-masked
    }
  }

  f32x16 acc[5];
#pragma unroll
  for (int k = 0; k < 5; ++k)
#pragma unroll
    for (int q = 0; q < 16; ++q) acc[k][q] = 0.f;

  for (int sv = 0; sv < 14; ++sv) {
    const int svo = sv * 16;
#pragma unroll
    for (int q = 0; q < 4; ++q) {
      const int n = w*4 + q;                       // each wave stages 4 n and 4 o
      u16* dsti = &lds[n*1288];
      u16* dstt = &lds[20608 + n*1160];
#pragma unroll
      for (int inst = 0; inst < 3; ++inst) {
        if (inst < 2 || lane < 32)                 // img: 160 chunks of 16B
          __builtin_amdgcn_global_load_lds((const u32*)(Ximg + ioff[q*3+inst] + svo),
                                           (u32*)(dsti + inst*512), 16, 0, 0);
        if (inst < 2 || lane < 16)                 // tmpl: 144 chunks of 16B
          __builtin_amdgcn_global_load_lds((const u32*)(TmplP + toff[q*3+inst] + svo),
                                           (u32*)(dstt + inst*512), 16, 0, 0);
      }
    }
    asm volatile("s_waitcnt vmcnt(0)" ::: "memory");
    __syncthreads();

    // 5-deep A-fragment ring along the diagonal r = i0 + u0 (4/5 frags reused)
    bf16x8 ar[5];
#pragma unroll
    for (int m = 0; m < 5; ++m)
      ar[m] = *(const bf16x8*)(&lds[aBase + 32*m]);
#pragma unroll
    for (int t = 0; t < 9; ++t) {
      bf16x8 bf = *(const bf16x8*)(&lds[bBase + 32*t]);
#pragma unroll
      for (int k = 0; k < 5; ++k)
        acc[k] = __builtin_amdgcn_mfma_f32_32x32x16_bf16(ar[(k+t)%5], bf, acc[k], 0, 0, 0);
      if (t < 8) ar[t%5] = *(const bf16x8*)(&lds[aBase + 32*(t+5)]);
    }
    __syncthreads();
  }

  // deterministic cross-wave fold in LDS (waves add sequentially)
  float* fl = (float*)lds;
  for (int z = tid; z < 5120; z += 256) fl[z] = 0.f;
  __syncthreads();
  for (int ww = 0; ww < 4; ++ww) {
    if (w == ww) {
#pragma unroll
      for (int k = 0; k < 5; ++k) {
        if (!(g == 3 && k == 4)) {       // g3 chain 4 duplicates i0=36: exclude
#pragma unroll
          for (int q = 0; q < 16; ++q)
            fl[k*1024 + q*64 + lane] += acc[k][q];
        }
      }
    }
    __syncthreads();
  }

  // emit 11 output rows [10g-1, 10g+9]; slabs [uq][g&1] are write-disjoint
  const int n = (tid >> 4) & 15;
  const int o = tid & 15;
  float* slab = partial + (uq*2 + (g & 1)) * OUT2;
  for (int ii = 0; ii < 11; ++ii) {
    const int i = 10*g - 1 + ii;
    if (i < 0 || i >= 37) continue;
    const int d = ii - 1;
    float v;
    if (!(d & 1)) {                       // diag: (uu,p)=(0,0)+(1,1)
      const int k = d >> 1;
      v = F_LD(k, n, o) + F_LD(k, n+16, o+16);
    } else {
      v = 0.f;
      if (d >= 1) v += F_LD((d-1) >> 1, n+16, o);   // (1,0) from left chain
      const int kr = (d+1) >> 1;
      if (kr <= 4) v += F_LD(kr, n, o+16);          // (0,1) from right chain
    }
    slab[(o*16 + n)*1369 + i*37 + j] = v;
  }
}

// ---------------- k3: reduce 6 partial slabs + scale -------------------------
__global__ void k3_reduce(const float* __restrict__ partial, float* __restrict__ out2) {
  const int idx = blockIdx.x*256 + threadIdx.x;
  float s = 0.f;
#pragma unroll
  for (int t = 0; t < 6; ++t) s += partial[t*OUT2 + idx];
  out2[idx] = s * (1.0f / 44944.0f);
}

extern "C" void kernel_launch(void* const* d_in, const int* in_sizes, int n_in,
                              void* d_out, int out_size, void* d_ws, size_t ws_size,
                              hipStream_t stream) {
  (void)in_sizes; (void)n_in; (void)out_size; (void)ws_size;
  const float* x   = (const float*)d_in[0];
  const float* ft  = (const float*)d_in[1];
  const float* fnt = (const float*)d_in[2];
  float* out = (float*)d_out;
  char*  ws  = (char*)d_ws;
  u16*   Ximg    = (u16*)ws;
  u16*   TmplP   = (u16*)(ws + TMPL_OFFB);
  float* partial = (float*)(ws + PART_OFFB);
  float* effw    = (float*)(ws + EFF_OFFB);

  hipFuncSetAttribute((const void*)k2_corr,
                      hipFuncAttributeMaxDynamicSharedMemorySize, 78336);

  k0_init<<<512, 256, 0, stream>>>(ft, fnt, partial, effw);
  k1_conv<<<dim3(17, 16), 256, 0, stream>>>(x, effw, out, Ximg, TmplP);
  k2_corr<<<444, 256, 78336, stream>>>(Ximg, TmplP, partial);
  k3_reduce<<<1369, 256, 0, stream>>>(partial, out + OUT1);
}